// Round 9
// baseline (173.475 us; speedup 1.0000x reference)
//
#include <hip/hip_runtime.h>

// ---------------------------------------------------------------------------
// GroupAgent fused pipeline v9, MI355X (gfx950), fp16 MFMA + f32 accumulate.
// Key change vs v8: final stage folds hn-scaling into the MFMA A-operand:
//   q[n,a] = sum_{h,e} (hn[n,h]*g[n,e]) * W[e,h,a]  -> per phase A' = hn.*g
//   (4 v_pk_mul_f16 per frag), MFMA accumulates straight into persistent qa.
// Deletes per-phase f32 scale-epilogue, hwbs, hv buffers, and the GRU hnT
// transpose. hwb folded as a K=256 GEMM (hn @ hwb2) in by==0's prologue.
// hwt/hbt/hwb2 stored [e-group][a][8] (conflict-free, no XOR swizzle).
// ---------------------------------------------------------------------------

typedef _Float16 half8 __attribute__((ext_vector_type(8)));
typedef float f32x4 __attribute__((ext_vector_type(4)));

#define MFMA16(a, b, c) __builtin_amdgcn_mfma_f32_16x16x32_f16((a), (b), (c), 0, 0, 0)

constexpr int NROWS = 16384;

__device__ __forceinline__ float sigmoidf_(float x) { return 1.0f / (1.0f + __expf(-x)); }

__device__ __forceinline__ void glds16(const void* g, void* l) {
    __builtin_amdgcn_global_load_lds((const __attribute__((address_space(1))) void*)g,
                                     (__attribute__((address_space(3))) void*)l, 16, 0, 0);
}

// ---------------- fused prep ----------------
// blocks: [0,4096) cvt-x | [4096,8192) cvt-h | [8192,10440) wtrans |
//         [10440,10824) wgru pack | [10824,11336) q zero | [11336,11344) hwb2
__global__ void prep_kernel(const float* __restrict__ x, const float* __restrict__ h,
                            const float* __restrict__ fc1_w, const float* __restrict__ hgw1,
                            const float* __restrict__ hgw2, const float* __restrict__ hbw,
                            const float* __restrict__ hww, const float* __restrict__ gwih,
                            const float* __restrict__ gwhh, const float* __restrict__ hwb,
                            _Float16* __restrict__ x16, _Float16* __restrict__ xh,
                            _Float16* __restrict__ w1t, _Float16* __restrict__ hg1t,
                            _Float16* __restrict__ hg2t, _Float16* __restrict__ hbt,
                            _Float16* __restrict__ hwt, _Float16* __restrict__ wgru2,
                            _Float16* __restrict__ hwb2, float* __restrict__ q) {
    __shared__ float tile[32][33];
    int b = blockIdx.x, tid = threadIdx.x;
    if (b < 4096) {
        int i = (b * 256 + tid) * 4;
        float4 v = *reinterpret_cast<const float4*>(x + i);
        x16[i + 0] = (_Float16)v.x; x16[i + 1] = (_Float16)v.y;
        x16[i + 2] = (_Float16)v.z; x16[i + 3] = (_Float16)v.w;
        return;
    }
    if (b < 8192) {
        int i = ((b - 4096) * 256 + tid) * 4;
        float4 v = *reinterpret_cast<const float4*>(h + i);
        int n = i >> 8, j = i & 255;
        _Float16* o = xh + n * 512 + 256 + j;
        o[0] = (_Float16)v.x; o[1] = (_Float16)v.y;
        o[2] = (_Float16)v.z; o[3] = (_Float16)v.w;
        return;
    }
    if (b >= 11336) {  // hwb2: [h 256][a 32] f32 -> f16 [(h>>3)][a][h&7]
        int i = ((b - 11336) * 256 + tid) * 4;
        float4 v = *reinterpret_cast<const float4*>(hwb + i);
        float arr[4] = {v.x, v.y, v.z, v.w};
#pragma unroll
        for (int j = 0; j < 4; j++) {
            int e = i + j, hh = e >> 5, a = e & 31;
            hwb2[(hh >> 3) * 256 + a * 8 + (hh & 7)] = (_Float16)arr[j];
        }
        return;
    }
    if (b >= 10824) {  // q zero: 512 blocks x 256 thr x 16 B = 2 MB
        int zb = b - 10824;
        float4 z = {0.f, 0.f, 0.f, 0.f};
        *reinterpret_cast<float4*>(q + (size_t)(zb * 256 + tid) * 4) = z;
        return;
    }
    int tx = tid & 31, ty = tid >> 5;  // 32 x 8
    if (b < 10440) {  // wtrans
        int bb = b - 8192;
        const float* src; _Float16* dst; int C, idx, mode;
        if (bb < 64)       { src = fc1_w; dst = w1t;  C = 256;  idx = bb;       mode = 0; }
        else if (bb < 128) { src = hgw1;  dst = hg1t; C = 256;  idx = bb - 64;  mode = 0; }
        else if (bb < 192) { src = hgw2;  dst = hg2t; C = 256;  idx = bb - 128; mode = 0; }
        else if (bb < 200) { src = hbw;   dst = hbt;  C = 32;   idx = bb - 192; mode = 1; }
        else               { src = hww;   dst = hwt;  C = 8192; idx = bb - 200; mode = 2; }
        int kb = (idx & 7) * 32, cb = (idx >> 3) * 32;
#pragma unroll
        for (int i = ty; i < 32; i += 8) tile[i][tx] = src[(kb + i) * C + cb + tx];
        __syncthreads();
#pragma unroll
        for (int i = ty; i < 32; i += 8) {
            int c = cb + i, k = kb + tx;
            if (mode == 0) {  // gemm weights: [c][k] with XOR swizzle
                dst[c * 256 + (k ^ ((c & 7) << 3))] = (_Float16)tile[tx][i];
            } else if (mode == 1) {  // hbt: [(k>>3)][a=c][k&7]
                dst[(k >> 3) * 256 + c * 8 + (k & 7)] = (_Float16)tile[tx][i];
            } else {  // hwt: [h][(e>>3)][a][e&7]
                int hh = c >> 5, a = c & 31;
                dst[hh * 8192 + (k >> 3) * 256 + a * 8 + (k & 7)] = (_Float16)tile[tx][i];
            }
        }
        return;
    }
    // wgru pack: wgru2[768][512]; col c: r-row=(c>>4)*48+(c&15), z=+16, n=+32.
    {
        int bb = b - 10440, job = bb >> 6, idx = bb & 63;
        int kb = (idx & 7) * 32, cb = (idx >> 3) * 32;
        const float* src = (job & 1) ? gwhh : gwih;
        int gsub = job >> 1;
        int coff = (gsub < 2) ? gsub * 256 : 512;
        int koff = (job & 1) * 256;
#pragma unroll
        for (int i = ty; i < 32; i += 8) tile[i][tx] = src[(kb + i) * 768 + coff + cb + tx];
        __syncthreads();
#pragma unroll
        for (int i = ty; i < 32; i += 8) {
            int c = cb + i;
            int row = (c >> 4) * 48 + gsub * 16 + (c & 15);
            int kk = kb + tx + koff;
            wgru2[row * 512 + (kk ^ ((row & 7) << 3))] = (_Float16)tile[tx][i];
        }
    }
}

// ---------------- GEMM + bias + activation, LDS-staged B, 4 row-tiles/wave ----------------
template <int ACT>  // 1 relu, 2 tanh
__global__ __launch_bounds__(256, 2) void gemm_lds_kernel(
    const _Float16* __restrict__ Am, const _Float16* __restrict__ Wt,
    const float* __restrict__ bias, _Float16* __restrict__ out16, int ONC) {
    __shared__ _Float16 Bs[64 * 256];  // 32 KB
    const int tid = threadIdx.x, wave = tid >> 6, lane = tid & 63;
    const int r = lane & 15, kg = lane >> 4;
    const int row0 = blockIdx.x * 256 + wave * 64;
    const int col0 = blockIdx.y * 64;
    const _Float16* src = Wt + col0 * 256;
#pragma unroll
    for (int it = 0; it < 8; ++it)
        glds16(src + it * 2048 + tid * 8, Bs + it * 2048 + tid * 8);
    asm volatile("s_waitcnt vmcnt(0)" ::: "memory");
    __syncthreads();

    f32x4 z = {0.f, 0.f, 0.f, 0.f};
    f32x4 acc[4][4];
#pragma unroll
    for (int t = 0; t < 4; t++)
#pragma unroll
        for (int j = 0; j < 4; j++) acc[t][j] = z;
    const int swz = (r & 7) << 4;
#pragma unroll
    for (int kb = 0; kb < 8; kb++) {
        half8 a[4], bm[4];
#pragma unroll
        for (int t = 0; t < 4; t++)
            a[t] = *reinterpret_cast<const half8*>(Am + (row0 + t * 16 + r) * 256 + kb * 32 + kg * 8);
#pragma unroll
        for (int j = 0; j < 4; j++)
            bm[j] = *reinterpret_cast<const half8*>(
                (const char*)Bs + (j * 16 + r) * 512 + ((kb * 64 + kg * 16) ^ swz));
#pragma unroll
        for (int t = 0; t < 4; t++)
#pragma unroll
            for (int j = 0; j < 4; j++) acc[t][j] = MFMA16(a[t], bm[j], acc[t][j]);
    }
#pragma unroll
    for (int j = 0; j < 4; j++) {
        int cc = col0 + j * 16 + r;
        float bv = bias[cc];
#pragma unroll
        for (int t = 0; t < 4; t++)
#pragma unroll
            for (int i = 0; i < 4; i++) {
                int rr = row0 + t * 16 + kg * 4 + i;
                float v = acc[t][j][i] + bv;
                if (ACT == 1) v = fmaxf(v, 0.0f);
                if (ACT == 2) v = tanhf(v);
                out16[rr * ONC + cc] = (_Float16)v;
            }
    }
}

// ---------------- fused GRU: 3-group pack (no zero FLOPs) ----------------
__global__ __launch_bounds__(256, 2) void gru_kernel(
    const _Float16* __restrict__ xh, const float* __restrict__ hf,
    const _Float16* __restrict__ wgru2, const float* __restrict__ bih,
    const float* __restrict__ bhh, _Float16* __restrict__ hn16) {
    __shared__ _Float16 Bs[48 * 512];  // 48 KB
    const int tid = threadIdx.x, wave = tid >> 6, lane = tid & 63;
    const int r = lane & 15, kg = lane >> 4;
    const int row0 = blockIdx.x * 256 + wave * 64;
    const int c0 = blockIdx.y * 16;
    const _Float16* src = wgru2 + (size_t)blockIdx.y * 48 * 512;
#pragma unroll
    for (int it = 0; it < 12; ++it)
        glds16(src + it * 2048 + tid * 8, Bs + it * 2048 + tid * 8);
    asm volatile("s_waitcnt vmcnt(0)" ::: "memory");
    __syncthreads();

    f32x4 z = {0.f, 0.f, 0.f, 0.f};
    f32x4 ar[4], az[4], ain[4], ahn[4];
#pragma unroll
    for (int t = 0; t < 4; t++) { ar[t] = z; az[t] = z; ain[t] = z; ahn[t] = z; }
    const int swz = (r & 7) << 4;
#pragma unroll
    for (int kb = 0; kb < 16; kb++) {
        half8 a[4];
#pragma unroll
        for (int t = 0; t < 4; t++)
            a[t] = *reinterpret_cast<const half8*>(xh + (row0 + t * 16 + r) * 512 + kb * 32 + kg * 8);
        const int c0b = (kb * 64 + kg * 16) ^ swz;
        half8 br = *reinterpret_cast<const half8*>((const char*)Bs + (r) * 1024 + c0b);
        half8 bz = *reinterpret_cast<const half8*>((const char*)Bs + (16 + r) * 1024 + c0b);
        half8 bn = *reinterpret_cast<const half8*>((const char*)Bs + (32 + r) * 1024 + c0b);
#pragma unroll
        for (int t = 0; t < 4; t++) {
            ar[t] = MFMA16(a[t], br, ar[t]);
            az[t] = MFMA16(a[t], bz, az[t]);
        }
        if (kb < 8) {
#pragma unroll
            for (int t = 0; t < 4; t++) ain[t] = MFMA16(a[t], bn, ain[t]);
        } else {
#pragma unroll
            for (int t = 0; t < 4; t++) ahn[t] = MFMA16(a[t], bn, ahn[t]);
        }
    }
    const int cc = c0 + r;
    float brz = bih[cc] + bhh[cc];
    float bzz = bih[256 + cc] + bhh[256 + cc];
    float bin = bih[512 + cc], bhn = bhh[512 + cc];
#pragma unroll
    for (int t = 0; t < 4; t++)
#pragma unroll
        for (int i = 0; i < 4; i++) {
            int rr = row0 + t * 16 + kg * 4 + i;
            float rg = sigmoidf_(ar[t][i] + brz);
            float zg = sigmoidf_(az[t][i] + bzz);
            float nn = tanhf(ain[t][i] + bin + rg * (ahn[t][i] + bhn));
            float v = (1.0f - zg) * nn + zg * hf[rr * 256 + cc];
            hn16[rr * 256 + cc] = (_Float16)v;
        }
}

// ---------------- fused final: A' = hn.*g folded into MFMA, ring-4, vmcnt(8) ----------
// grid 512 = 64 bx x 8 by. 2 blocks/CU. Wave = 64 rows x 32 actions.
// qa accumulates IN the MFMA C operand across all 32 phases.
__global__ __launch_bounds__(256)
__attribute__((amdgpu_waves_per_eu(2, 2))) void final_kernel(
    const _Float16* __restrict__ g16, const _Float16* __restrict__ hwt,
    const _Float16* __restrict__ hwb2, const _Float16* __restrict__ hbt,
    const float* __restrict__ hbb, const _Float16* __restrict__ hn16,
    float* __restrict__ q) {
    __shared__ _Float16 Bs[4][8192];   // 64 KB ring-4, 1 h (16 KB) per chunk
    const int bid = blockIdx.x;
    const int by = bid & 7, bx = bid >> 3;
    const int tid = threadIdx.x, wave = tid >> 6, lane = tid & 63;
    const int r = lane & 15, kg = lane >> 4;
    const int row0 = bx * 256 + wave * 64;
    const int hbase = by * 32;

    // ---- prologue: stage chunk0; load ga; b_dyn + hwb GEMMs on by==0 ----
#pragma unroll
    for (int it = 0; it < 4; ++it) {
        int e = it * 2048 + tid * 8;
        glds16(hwt + (size_t)hbase * 8192 + e, &Bs[0][0] + e);
    }

    half8 ga[4][8];
#pragma unroll
    for (int t = 0; t < 4; t++)
#pragma unroll
        for (int kb = 0; kb < 8; kb++)
            ga[t][kb] = *reinterpret_cast<const half8*>(
                g16 + (row0 + t * 16 + r) * 256 + kb * 32 + kg * 8);

    f32x4 qa[4][2];
    if (by == 0) {
        float b0v = hbb[r], b1v = hbb[16 + r];
#pragma unroll
        for (int t = 0; t < 4; t++) {
            qa[t][0] = {b0v, b0v, b0v, b0v};
            qa[t][1] = {b1v, b1v, b1v, b1v};
        }
        // b_dyn = g @ hb_w   (hbt layout [(e>>3)][a][e&7])
#pragma unroll
        for (int kb = 0; kb < 8; kb++) {
            const char* hp = (const char*)hbt + (kb * 4 + kg) * 512 + r * 16;
            half8 hb0 = *reinterpret_cast<const half8*>(hp);
            half8 hb1 = *reinterpret_cast<const half8*>(hp + 256);
#pragma unroll
            for (int t = 0; t < 4; t++) {
                qa[t][0] = MFMA16(ga[t][kb], hb0, qa[t][0]);
                qa[t][1] = MFMA16(ga[t][kb], hb1, qa[t][1]);
            }
        }
        // hwb term = hn @ hwb2  (K = 256 over h)
#pragma unroll
        for (int kb = 0; kb < 8; kb++) {
            half8 an[4];
#pragma unroll
            for (int t = 0; t < 4; t++)
                an[t] = *reinterpret_cast<const half8*>(
                    hn16 + (row0 + t * 16 + r) * 256 + kb * 32 + kg * 8);
            const char* wp = (const char*)hwb2 + (kb * 4 + kg) * 512 + r * 16;
            half8 wb0 = *reinterpret_cast<const half8*>(wp);
            half8 wb1 = *reinterpret_cast<const half8*>(wp + 256);
#pragma unroll
            for (int t = 0; t < 4; t++) {
                qa[t][0] = MFMA16(an[t], wb0, qa[t][0]);
                qa[t][1] = MFMA16(an[t], wb1, qa[t][1]);
            }
        }
    } else {
        f32x4 z = {0.f, 0.f, 0.f, 0.f};
#pragma unroll
        for (int t = 0; t < 4; t++) { qa[t][0] = z; qa[t][1] = z; }
    }
#pragma unroll
    for (int t = 0; t < 4; t++)
#pragma unroll
        for (int kb = 0; kb < 8; kb++)
            asm volatile("" : "+v"(ga[t][kb]));  // keep resident

    asm volatile("s_waitcnt vmcnt(0)" ::: "memory");
    __builtin_amdgcn_s_barrier();

    // ---- pre-issue: chunk1 glds (4) + hn(0) scalars (4) -> 8 outstanding ----
#pragma unroll
    for (int it = 0; it < 4; ++it) {
        int e = it * 2048 + tid * 8;
        glds16(hwt + (size_t)(hbase + 1) * 8192 + e, &Bs[1][0] + e);
    }
    const _Float16* hnp = hn16 + (size_t)(row0 + r) * 256 + hbase;  // + t*4096 + h
    _Float16 hnA[4], hnB[4];
#pragma unroll
    for (int t = 0; t < 4; t++) hnA[t] = hnp[t * 4096];

    // ---- main loop: issue glds(h+2) + hn(h+1); counted wait; barrier; MFMA ----
    auto phase = [&](int h, _Float16* hnC, _Float16* hnN) {
        if (h < 30) {
            const _Float16* srcp = hwt + (size_t)(hbase + h + 2) * 8192;
            _Float16* dst = &Bs[(h + 2) & 3][0];
#pragma unroll
            for (int it = 0; it < 4; ++it) {
                int e = it * 2048 + tid * 8;
                glds16(srcp + e, dst + e);
            }
        }
        if (h < 31) {
#pragma unroll
            for (int t = 0; t < 4; t++) hnN[t] = hnp[t * 4096 + h + 1];
        }
        if (h < 30)
            asm volatile("s_waitcnt vmcnt(8)" ::: "memory");
        else if (h == 30)
            asm volatile("s_waitcnt vmcnt(4)" ::: "memory");
        else
            asm volatile("s_waitcnt vmcnt(0)" ::: "memory");
        __builtin_amdgcn_s_barrier();

        const char* bp = (const char*)&Bs[h & 3][0];
        half8 s[4];
#pragma unroll
        for (int t = 0; t < 4; t++) {
            _Float16 v = hnC[t];
            s[t] = (half8){v, v, v, v, v, v, v, v};
        }
        __builtin_amdgcn_s_setprio(1);
#pragma unroll
        for (int kb = 0; kb < 8; kb++) {
            const char* kp = bp + (kb * 4 + kg) * 512 + r * 16;
            half8 b0 = *reinterpret_cast<const half8*>(kp);
            half8 b1 = *reinterpret_cast<const half8*>(kp + 256);
#pragma unroll
            for (int t = 0; t < 4; t++) {
                half8 ap = ga[t][kb] * s[t];  // 4x v_pk_mul_f16
                qa[t][0] = MFMA16(ap, b0, qa[t][0]);
                qa[t][1] = MFMA16(ap, b1, qa[t][1]);
            }
        }
        __builtin_amdgcn_s_setprio(0);
    };
    for (int h = 0; h < 32; h += 2) {
        phase(h, hnA, hnB);
        phase(h + 1, hnB, hnA);
    }

#pragma unroll
    for (int t = 0; t < 4; t++)
#pragma unroll
        for (int i = 0; i < 4; i++) {
            int rr = row0 + t * 16 + kg * 4 + i;
            atomicAdd(&q[rr * 32 + r], qa[t][0][i]);
            atomicAdd(&q[rr * 32 + 16 + r], qa[t][1][i]);
        }
}

// ---------------------------------------------------------------------------
extern "C" void kernel_launch(void* const* d_in, const int* in_sizes, int n_in,
                              void* d_out, int out_size, void* d_ws, size_t ws_size,
                              hipStream_t stream) {
    const float* x = (const float*)d_in[0];
    const float* h = (const float*)d_in[1];
    const float* fc1_w = (const float*)d_in[2];
    const float* fc1_b = (const float*)d_in[3];
    const float* gwih = (const float*)d_in[4];
    const float* gbih = (const float*)d_in[5];
    const float* gwhh = (const float*)d_in[6];
    const float* gbhh = (const float*)d_in[7];
    const float* hgw1 = (const float*)d_in[8];
    const float* hgb1 = (const float*)d_in[9];
    const float* hgw2 = (const float*)d_in[10];
    const float* hgb2 = (const float*)d_in[11];
    const float* hbw = (const float*)d_in[12];
    const float* hbb = (const float*)d_in[13];
    const float* hww = (const float*)d_in[14];
    const float* hwb = (const float*)d_in[15];
    float* q = (float*)d_out;

    char* p = (char*)d_ws;
    auto alloc = [&](size_t bytes) { char* r = p; p += (bytes + 255) & ~255ULL; return r; };
    _Float16* x16 = (_Float16*)alloc((size_t)NROWS * 256 * 2);
    _Float16* xh = (_Float16*)alloc((size_t)NROWS * 512 * 2);
    _Float16* w1t = (_Float16*)alloc((size_t)256 * 256 * 2);
    _Float16* wgru2 = (_Float16*)alloc((size_t)768 * 512 * 2);
    _Float16* hg1t = (_Float16*)alloc((size_t)256 * 256 * 2);
    _Float16* hg2t = (_Float16*)alloc((size_t)256 * 256 * 2);
    _Float16* hbt = (_Float16*)alloc((size_t)32 * 256 * 2);
    _Float16* hwt = (_Float16*)alloc((size_t)8192 * 256 * 2 + 65536);
    _Float16* hwb2 = (_Float16*)alloc((size_t)8192 * 2);
    _Float16* hn16 = (_Float16*)alloc((size_t)NROWS * 256 * 2);
    _Float16* t16 = (_Float16*)alloc((size_t)NROWS * 256 * 2);
    _Float16* g16 = (_Float16*)alloc((size_t)NROWS * 256 * 2);

    // ---- prep: ONE kernel ----
    prep_kernel<<<11344, 256, 0, stream>>>(x, h, fc1_w, hgw1, hgw2, hbw, hww, gwih, gwhh,
                                           hwb, x16, xh, w1t, hg1t, hg2t, hbt, hwt, wgru2,
                                           hwb2, q);

    // ---- stage 1: x1 = relu(x @ fc1_w + b) -> xh[:, 0:256] ----
    gemm_lds_kernel<1><<<dim3(64, 4), 256, 0, stream>>>(x16, w1t, fc1_b, xh, 512);

    // ---- stage 2: GRU ----
    gru_kernel<<<dim3(64, 16), 256, 0, stream>>>(xh, h, wgru2, gbih, gbhh, hn16);

    // ---- stage 3/4: hypernet latent ----
    gemm_lds_kernel<1><<<dim3(64, 4), 256, 0, stream>>>(hn16, hg1t, hgb1, t16, 256);
    gemm_lds_kernel<2><<<dim3(64, 4), 256, 0, stream>>>(t16, hg2t, hgb2, g16, 256);

    // ---- stage 5: fused q = b_dyn + hwb-term + einsum (one GEMM family) ----
    final_kernel<<<512, 256, 0, stream>>>(g16, hwt, hwb2, hbt, hbb, hn16, q);
}

// Round 10
// 158.101 us; speedup vs baseline: 1.0972x; 1.0972x over previous
//
#include <hip/hip_runtime.h>

// ---------------------------------------------------------------------------
// GroupAgent fused pipeline v10, MI355X (gfx950), fp16 MFMA + f32 accumulate.
// v10 = v8 structure (best: 159.5us) + v9's bank-conflict-free B layout
// (measured 4.19M -> 0 conflict cycles).
//   prep (ONE kernel): cvt x/h, weight transposes, gru 3-group pack, q zero.
//   1. x1 = relu(x @ fc1_w + b)  -> xh[:, 0:256]
//   2. GRU: 192-MFMA tile + fused hnT transpose
//   3. t = relu(hn @ hg_w1 + b);  4. g = tanh(t @ hg_w2 + b)
//   5. final: ring-4 LDS, counted vmcnt(8), w-accum MFMA (init = hw_b),
//      f32 scale epilogue, hv double-buffered regs from hnT16.
// hwt/hbt layout [e>>3][a][e&7] => ds_read_b128 conflict-free (v9-verified).
// gemm/gru weights [col][K] XOR-swizzled as before.
// ---------------------------------------------------------------------------

typedef _Float16 half8 __attribute__((ext_vector_type(8)));
typedef _Float16 half4 __attribute__((ext_vector_type(4)));
typedef float f32x4 __attribute__((ext_vector_type(4)));

#define MFMA16(a, b, c) __builtin_amdgcn_mfma_f32_16x16x32_f16((a), (b), (c), 0, 0, 0)

constexpr int NROWS = 16384;

__device__ __forceinline__ float sigmoidf_(float x) { return 1.0f / (1.0f + __expf(-x)); }

__device__ __forceinline__ void glds16(const void* g, void* l) {
    __builtin_amdgcn_global_load_lds((const __attribute__((address_space(1))) void*)g,
                                     (__attribute__((address_space(3))) void*)l, 16, 0, 0);
}

// ---------------- fused prep ----------------
// blocks: [0,4096) cvt-x | [4096,8192) cvt-h | [8192,10440) wtrans |
//         [10440,10824) wgru pack | [10824,11336) q zero
__global__ void prep_kernel(const float* __restrict__ x, const float* __restrict__ h,
                            const float* __restrict__ fc1_w, const float* __restrict__ hgw1,
                            const float* __restrict__ hgw2, const float* __restrict__ hbw,
                            const float* __restrict__ hww, const float* __restrict__ gwih,
                            const float* __restrict__ gwhh, _Float16* __restrict__ x16,
                            _Float16* __restrict__ xh, _Float16* __restrict__ w1t,
                            _Float16* __restrict__ hg1t, _Float16* __restrict__ hg2t,
                            _Float16* __restrict__ hbt, _Float16* __restrict__ hwt,
                            _Float16* __restrict__ wgru2, float* __restrict__ q) {
    __shared__ float tile[32][33];
    int b = blockIdx.x, tid = threadIdx.x;
    if (b < 4096) {
        int i = (b * 256 + tid) * 4;
        float4 v = *reinterpret_cast<const float4*>(x + i);
        x16[i + 0] = (_Float16)v.x; x16[i + 1] = (_Float16)v.y;
        x16[i + 2] = (_Float16)v.z; x16[i + 3] = (_Float16)v.w;
        return;
    }
    if (b < 8192) {
        int i = ((b - 4096) * 256 + tid) * 4;
        float4 v = *reinterpret_cast<const float4*>(h + i);
        int n = i >> 8, j = i & 255;
        _Float16* o = xh + n * 512 + 256 + j;
        o[0] = (_Float16)v.x; o[1] = (_Float16)v.y;
        o[2] = (_Float16)v.z; o[3] = (_Float16)v.w;
        return;
    }
    if (b >= 10824) {  // q zero
        int zb = b - 10824;
        float4 z = {0.f, 0.f, 0.f, 0.f};
        *reinterpret_cast<float4*>(q + (size_t)(zb * 256 + tid) * 4) = z;
        return;
    }
    int tx = tid & 31, ty = tid >> 5;  // 32 x 8
    if (b < 10440) {  // wtrans
        int bb = b - 8192;
        const float* src; _Float16* dst; int C, idx, mode;
        if (bb < 64)       { src = fc1_w; dst = w1t;  C = 256;  idx = bb;       mode = 0; }
        else if (bb < 128) { src = hgw1;  dst = hg1t; C = 256;  idx = bb - 64;  mode = 0; }
        else if (bb < 192) { src = hgw2;  dst = hg2t; C = 256;  idx = bb - 128; mode = 0; }
        else if (bb < 200) { src = hbw;   dst = hbt;  C = 32;   idx = bb - 192; mode = 1; }
        else               { src = hww;   dst = hwt;  C = 8192; idx = bb - 200; mode = 2; }
        int kb = (idx & 7) * 32, cb = (idx >> 3) * 32;
#pragma unroll
        for (int i = ty; i < 32; i += 8) tile[i][tx] = src[(kb + i) * C + cb + tx];
        __syncthreads();
#pragma unroll
        for (int i = ty; i < 32; i += 8) {
            int c = cb + i, k = kb + tx;
            if (mode == 0) {  // gemm weights: [c][k], XOR swizzle
                dst[c * 256 + (k ^ ((c & 7) << 3))] = (_Float16)tile[tx][i];
            } else if (mode == 1) {  // hbt: [(e>>3)][a][e&7], e=k, a=c
                dst[(k >> 3) * 256 + c * 8 + (k & 7)] = (_Float16)tile[tx][i];
            } else {  // hwt: [h][(e>>3)][a][e&7], h=c>>5, a=c&31, e=k
                int hh = c >> 5, a = c & 31;
                dst[hh * 8192 + (k >> 3) * 256 + a * 8 + (k & 7)] = (_Float16)tile[tx][i];
            }
        }
        return;
    }
    // wgru pack: wgru2[768][512]; col c: r-row=(c>>4)*48+(c&15), z=+16, n=+32.
    {
        int bb = b - 10440, job = bb >> 6, idx = bb & 63;
        int kb = (idx & 7) * 32, cb = (idx >> 3) * 32;
        const float* src = (job & 1) ? gwhh : gwih;
        int gsub = job >> 1;
        int coff = (gsub < 2) ? gsub * 256 : 512;
        int koff = (job & 1) * 256;
#pragma unroll
        for (int i = ty; i < 32; i += 8) tile[i][tx] = src[(kb + i) * 768 + coff + cb + tx];
        __syncthreads();
#pragma unroll
        for (int i = ty; i < 32; i += 8) {
            int c = cb + i;
            int row = (c >> 4) * 48 + gsub * 16 + (c & 15);
            int kk = kb + tx + koff;
            wgru2[row * 512 + (kk ^ ((row & 7) << 3))] = (_Float16)tile[tx][i];
        }
    }
}

// ---------------- GEMM + bias + activation, LDS-staged B, 4 row-tiles/wave ----------------
template <int ACT>  // 1 relu, 2 tanh
__global__ __launch_bounds__(256, 2) void gemm_lds_kernel(
    const _Float16* __restrict__ Am, const _Float16* __restrict__ Wt,
    const float* __restrict__ bias, _Float16* __restrict__ out16, int ONC) {
    __shared__ _Float16 Bs[64 * 256];  // 32 KB
    const int tid = threadIdx.x, wave = tid >> 6, lane = tid & 63;
    const int r = lane & 15, kg = lane >> 4;
    const int row0 = blockIdx.x * 256 + wave * 64;
    const int col0 = blockIdx.y * 64;
    const _Float16* src = Wt + col0 * 256;
#pragma unroll
    for (int it = 0; it < 8; ++it)
        glds16(src + it * 2048 + tid * 8, Bs + it * 2048 + tid * 8);
    asm volatile("s_waitcnt vmcnt(0)" ::: "memory");
    __syncthreads();

    f32x4 z = {0.f, 0.f, 0.f, 0.f};
    f32x4 acc[4][4];
#pragma unroll
    for (int t = 0; t < 4; t++)
#pragma unroll
        for (int j = 0; j < 4; j++) acc[t][j] = z;
    const int swz = (r & 7) << 4;
#pragma unroll
    for (int kb = 0; kb < 8; kb++) {
        half8 a[4], bm[4];
#pragma unroll
        for (int t = 0; t < 4; t++)
            a[t] = *reinterpret_cast<const half8*>(Am + (row0 + t * 16 + r) * 256 + kb * 32 + kg * 8);
#pragma unroll
        for (int j = 0; j < 4; j++)
            bm[j] = *reinterpret_cast<const half8*>(
                (const char*)Bs + (j * 16 + r) * 512 + ((kb * 64 + kg * 16) ^ swz));
#pragma unroll
        for (int t = 0; t < 4; t++)
#pragma unroll
            for (int j = 0; j < 4; j++) acc[t][j] = MFMA16(a[t], bm[j], acc[t][j]);
    }
#pragma unroll
    for (int j = 0; j < 4; j++) {
        int cc = col0 + j * 16 + r;
        float bv = bias[cc];
#pragma unroll
        for (int t = 0; t < 4; t++)
#pragma unroll
            for (int i = 0; i < 4; i++) {
                int rr = row0 + t * 16 + kg * 4 + i;
                float v = acc[t][j][i] + bv;
                if (ACT == 1) v = fmaxf(v, 0.0f);
                if (ACT == 2) v = tanhf(v);
                out16[rr * ONC + cc] = (_Float16)v;
            }
    }
}

// ---------------- fused GRU: 3-group pack + fused hnT transpose ----------------
__global__ __launch_bounds__(256, 2) void gru_kernel(
    const _Float16* __restrict__ xh, const float* __restrict__ hf,
    const _Float16* __restrict__ wgru2, const float* __restrict__ bih,
    const float* __restrict__ bhh, _Float16* __restrict__ hn16,
    _Float16* __restrict__ hnT16) {
    __shared__ _Float16 Bs[48 * 512];  // 48 KB (reused for transpose bounce)
    const int tid = threadIdx.x, wave = tid >> 6, lane = tid & 63;
    const int r = lane & 15, kg = lane >> 4;
    const int row0 = blockIdx.x * 256 + wave * 64;
    const int c0 = blockIdx.y * 16;
    const _Float16* src = wgru2 + (size_t)blockIdx.y * 48 * 512;
#pragma unroll
    for (int it = 0; it < 12; ++it)
        glds16(src + it * 2048 + tid * 8, Bs + it * 2048 + tid * 8);
    asm volatile("s_waitcnt vmcnt(0)" ::: "memory");
    __syncthreads();

    f32x4 z = {0.f, 0.f, 0.f, 0.f};
    f32x4 ar[4], az[4], ain[4], ahn[4];
#pragma unroll
    for (int t = 0; t < 4; t++) { ar[t] = z; az[t] = z; ain[t] = z; ahn[t] = z; }
    const int swz = (r & 7) << 4;
#pragma unroll
    for (int kb = 0; kb < 16; kb++) {
        half8 a[4];
#pragma unroll
        for (int t = 0; t < 4; t++)
            a[t] = *reinterpret_cast<const half8*>(xh + (row0 + t * 16 + r) * 512 + kb * 32 + kg * 8);
        const int c0b = (kb * 64 + kg * 16) ^ swz;
        half8 br = *reinterpret_cast<const half8*>((const char*)Bs + (r) * 1024 + c0b);
        half8 bz = *reinterpret_cast<const half8*>((const char*)Bs + (16 + r) * 1024 + c0b);
        half8 bn = *reinterpret_cast<const half8*>((const char*)Bs + (32 + r) * 1024 + c0b);
#pragma unroll
        for (int t = 0; t < 4; t++) {
            ar[t] = MFMA16(a[t], br, ar[t]);
            az[t] = MFMA16(a[t], bz, az[t]);
        }
        if (kb < 8) {
#pragma unroll
            for (int t = 0; t < 4; t++) ain[t] = MFMA16(a[t], bn, ain[t]);
        } else {
#pragma unroll
            for (int t = 0; t < 4; t++) ahn[t] = MFMA16(a[t], bn, ahn[t]);
        }
    }
    const int cc = c0 + r;
    float brz = bih[cc] + bhh[cc];
    float bzz = bih[256 + cc] + bhh[256 + cc];
    float bin = bih[512 + cc], bhn = bhh[512 + cc];
    _Float16 vs[4][4];
#pragma unroll
    for (int t = 0; t < 4; t++)
#pragma unroll
        for (int i = 0; i < 4; i++) {
            int rr = row0 + t * 16 + kg * 4 + i;
            float rg = sigmoidf_(ar[t][i] + brz);
            float zg = sigmoidf_(az[t][i] + bzz);
            float nn = tanhf(ain[t][i] + bin + rg * (ahn[t][i] + bhn));
            float v = (1.0f - zg) * nn + zg * hf[rr * 256 + cc];
            _Float16 v16 = (_Float16)v;
            hn16[rr * 256 + cc] = v16;
            vs[t][i] = v16;
        }
    // fused transpose: [16 cols][256 rows] tile (pad 264), coalesced hnT write
    __syncthreads();
    _Float16* tileb = Bs;
#pragma unroll
    for (int t = 0; t < 4; t++)
#pragma unroll
        for (int i = 0; i < 4; i++)
            tileb[r * 264 + wave * 64 + t * 16 + kg * 4 + i] = vs[t][i];
    __syncthreads();
    {
        int trow = tid >> 4, chunk = tid & 15;
        half8 v0 = *reinterpret_cast<const half8*>(tileb + trow * 264 + chunk * 16);
        half8 v1 = *reinterpret_cast<const half8*>(tileb + trow * 264 + chunk * 16 + 8);
        size_t dst = (size_t)(c0 + trow) * NROWS + blockIdx.x * 256 + chunk * 16;
        *reinterpret_cast<half8*>(hnT16 + dst) = v0;
        *reinterpret_cast<half8*>(hnT16 + dst + 8) = v1;
    }
}

// ---------------- fused final: ring-4, counted vmcnt(8), conflict-free B ------
// grid 512 = 64 bx x 8 by (by=bid&7, XCD-pinned 32-h slice). 2 blocks/CU.
// Wave = 64 rows x 32 actions. ga resident. hv double-buffered regs.
__global__ __launch_bounds__(256)
__attribute__((amdgpu_waves_per_eu(2, 2))) void final_kernel(
    const _Float16* __restrict__ g16, const _Float16* __restrict__ hwt,
    const float* __restrict__ hwb, const _Float16* __restrict__ hbt,
    const float* __restrict__ hbb, const _Float16* __restrict__ hnT16,
    float* __restrict__ q) {
    __shared__ _Float16 Bs[4][8192];   // 64 KB ring-4, 1 h per chunk
    __shared__ float hwbs[1024];       // 4 KB
    const int bid = blockIdx.x;
    const int by = bid & 7, bx = bid >> 3;
    const int tid = threadIdx.x, wave = tid >> 6, lane = tid & 63;
    const int r = lane & 15, kg = lane >> 4;
    const int row0 = bx * 256 + wave * 64;
    const int hbase = by * 32;

    // ---- prologue: stage chunk0 + hwbs; load ga; b_dyn on by==0; drain ----
#pragma unroll
    for (int it = 0; it < 4; ++it) {
        int e = it * 2048 + tid * 8;
        glds16(hwt + (size_t)hbase * 8192 + e, &Bs[0][0] + e);
    }
    glds16(hwb + hbase * 32 + tid * 4, hwbs + tid * 4);

    half8 ga[4][8];
#pragma unroll
    for (int t = 0; t < 4; t++)
#pragma unroll
        for (int kb = 0; kb < 8; kb++)
            ga[t][kb] = *reinterpret_cast<const half8*>(
                g16 + (row0 + t * 16 + r) * 256 + kb * 32 + kg * 8);

    f32x4 qa[4][2];
    if (by == 0) {
        float b0v = hbb[r], b1v = hbb[16 + r];
#pragma unroll
        for (int t = 0; t < 4; t++) {
            qa[t][0] = {b0v, b0v, b0v, b0v};
            qa[t][1] = {b1v, b1v, b1v, b1v};
        }
#pragma unroll
        for (int kb = 0; kb < 8; kb++) {
            const char* hp = (const char*)hbt + (kb * 4 + kg) * 512 + r * 16;
            half8 hb0 = *reinterpret_cast<const half8*>(hp);
            half8 hb1 = *reinterpret_cast<const half8*>(hp + 256);
#pragma unroll
            for (int t = 0; t < 4; t++) {
                qa[t][0] = MFMA16(ga[t][kb], hb0, qa[t][0]);
                qa[t][1] = MFMA16(ga[t][kb], hb1, qa[t][1]);
            }
        }
    } else {
        f32x4 z = {0.f, 0.f, 0.f, 0.f};
#pragma unroll
        for (int t = 0; t < 4; t++) { qa[t][0] = z; qa[t][1] = z; }
    }
#pragma unroll
    for (int t = 0; t < 4; t++)
#pragma unroll
        for (int kb = 0; kb < 8; kb++)
            asm volatile("" : "+v"(ga[t][kb]));  // keep resident

    asm volatile("s_waitcnt vmcnt(0)" ::: "memory");
    __builtin_amdgcn_s_barrier();

    // ---- pre-issue pipeline: glds(1) then hv(0); queue = 8 ----
#pragma unroll
    for (int it = 0; it < 4; ++it) {
        int e = it * 2048 + tid * 8;
        glds16(hwt + (size_t)(hbase + 1) * 8192 + e, &Bs[1][0] + e);
    }
    const _Float16* hvbase = hnT16 + (size_t)hbase * NROWS + bx * 256 + wave * 64 + kg * 4;
    half4 hvA[4], hvB[4];
#pragma unroll
    for (int t = 0; t < 4; t++) hvA[t] = *reinterpret_cast<const half4*>(hvbase + t * 16);

    // ---- main loop: issue glds(h+2), hv(h+1); counted wait; barrier; compute ----
    auto phase = [&](int h, half4* hvC, half4* hvN) {
        if (h < 30) {
            const _Float16* srcp = hwt + (size_t)(hbase + h + 2) * 8192;
            _Float16* dst = &Bs[(h + 2) & 3][0];
#pragma unroll
            for (int it = 0; it < 4; ++it) {
                int e = it * 2048 + tid * 8;
                glds16(srcp + e, dst + e);
            }
        }
        if (h < 31) {
            const _Float16* hp = hvbase + (size_t)(h + 1) * NROWS;
#pragma unroll
            for (int t = 0; t < 4; t++) hvN[t] = *reinterpret_cast<const half4*>(hp + t * 16);
        }
        if (h < 30)
            asm volatile("s_waitcnt vmcnt(8)" ::: "memory");
        else if (h == 30)
            asm volatile("s_waitcnt vmcnt(4)" ::: "memory");
        else
            asm volatile("s_waitcnt vmcnt(0)" ::: "memory");
        __builtin_amdgcn_s_barrier();

        const char* bp = (const char*)&Bs[h & 3][0];
        float wb0 = hwbs[(h << 5) + r], wb1 = hwbs[(h << 5) + 16 + r];
        f32x4 w0[4], w1[4];
#pragma unroll
        for (int t = 0; t < 4; t++) {
            w0[t] = {wb0, wb0, wb0, wb0};
            w1[t] = {wb1, wb1, wb1, wb1};
        }
        __builtin_amdgcn_s_setprio(1);
#pragma unroll
        for (int kb = 0; kb < 8; kb++) {
            const char* kp = bp + (kb * 4 + kg) * 512 + r * 16;  // conflict-free
            half8 b0 = *reinterpret_cast<const half8*>(kp);
            half8 b1 = *reinterpret_cast<const half8*>(kp + 256);
#pragma unroll
            for (int t = 0; t < 4; t++) {
                w0[t] = MFMA16(ga[t][kb], b0, w0[t]);
                w1[t] = MFMA16(ga[t][kb], b1, w1[t]);
            }
        }
        __builtin_amdgcn_s_setprio(0);
#pragma unroll
        for (int t = 0; t < 4; t++)
#pragma unroll
            for (int i = 0; i < 4; i++) {
                float hvf = (float)hvC[t][i];
                qa[t][0][i] += hvf * w0[t][i];
                qa[t][1][i] += hvf * w1[t][i];
            }
    };
    for (int h = 0; h < 32; h += 2) {
        phase(h, hvA, hvB);
        phase(h + 1, hvB, hvA);
    }

#pragma unroll
    for (int t = 0; t < 4; t++)
#pragma unroll
        for (int i = 0; i < 4; i++) {
            int rr = row0 + t * 16 + kg * 4 + i;
            atomicAdd(&q[rr * 32 + r], qa[t][0][i]);
            atomicAdd(&q[rr * 32 + 16 + r], qa[t][1][i]);
        }
}

// ---------------------------------------------------------------------------
extern "C" void kernel_launch(void* const* d_in, const int* in_sizes, int n_in,
                              void* d_out, int out_size, void* d_ws, size_t ws_size,
                              hipStream_t stream) {
    const float* x = (const float*)d_in[0];
    const float* h = (const float*)d_in[1];
    const float* fc1_w = (const float*)d_in[2];
    const float* fc1_b = (const float*)d_in[3];
    const float* gwih = (const float*)d_in[4];
    const float* gbih = (const float*)d_in[5];
    const float* gwhh = (const float*)d_in[6];
    const float* gbhh = (const float*)d_in[7];
    const float* hgw1 = (const float*)d_in[8];
    const float* hgb1 = (const float*)d_in[9];
    const float* hgw2 = (const float*)d_in[10];
    const float* hgb2 = (const float*)d_in[11];
    const float* hbw = (const float*)d_in[12];
    const float* hbb = (const float*)d_in[13];
    const float* hww = (const float*)d_in[14];
    const float* hwb = (const float*)d_in[15];
    float* q = (float*)d_out;

    char* p = (char*)d_ws;
    auto alloc = [&](size_t bytes) { char* r = p; p += (bytes + 255) & ~255ULL; return r; };
    _Float16* x16 = (_Float16*)alloc((size_t)NROWS * 256 * 2);
    _Float16* xh = (_Float16*)alloc((size_t)NROWS * 512 * 2);
    _Float16* w1t = (_Float16*)alloc((size_t)256 * 256 * 2);
    _Float16* wgru2 = (_Float16*)alloc((size_t)768 * 512 * 2);
    _Float16* hg1t = (_Float16*)alloc((size_t)256 * 256 * 2);
    _Float16* hg2t = (_Float16*)alloc((size_t)256 * 256 * 2);
    _Float16* hbt = (_Float16*)alloc((size_t)32 * 256 * 2);
    _Float16* hwt = (_Float16*)alloc((size_t)8192 * 256 * 2 + 65536);  // +pad: tail OOB
    _Float16* hn16 = (_Float16*)alloc((size_t)NROWS * 256 * 2);
    _Float16* hnT16 = (_Float16*)alloc((size_t)256 * NROWS * 2);
    _Float16* t16 = (_Float16*)alloc((size_t)NROWS * 256 * 2);
    _Float16* g16 = (_Float16*)alloc((size_t)NROWS * 256 * 2);

    // ---- prep: ONE kernel ----
    prep_kernel<<<11336, 256, 0, stream>>>(x, h, fc1_w, hgw1, hgw2, hbw, hww, gwih, gwhh,
                                           x16, xh, w1t, hg1t, hg2t, hbt, hwt, wgru2, q);

    // ---- stage 1: x1 = relu(x @ fc1_w + b) -> xh[:, 0:256] ----
    gemm_lds_kernel<1><<<dim3(64, 4), 256, 0, stream>>>(x16, w1t, fc1_b, xh, 512);

    // ---- stage 2: GRU (+ fused hnT transpose) ----
    gru_kernel<<<dim3(64, 16), 256, 0, stream>>>(xh, h, wgru2, gbih, gbhh, hn16, hnT16);

    // ---- stage 3/4: hypernet latent ----
    gemm_lds_kernel<1><<<dim3(64, 4), 256, 0, stream>>>(hn16, hg1t, hgb1, t16, 256);
    gemm_lds_kernel<2><<<dim3(64, 4), 256, 0, stream>>>(t16, hg2t, hgb2, g16, 256);

    // ---- stage 5: fused b_dyn + w_dyn einsum ----
    final_kernel<<<512, 256, 0, stream>>>(g16, hwt, hwb, hbt, hbb, hnT16, q);
}